// Round 11
// baseline (125.262 us; speedup 1.0000x reference)
//
#include <hip/hip_runtime.h>
#include <stdint.h>

typedef unsigned long long u64;
typedef unsigned int u32;

#define NQ 16384
#define ND 16384
#define KNB 32                  // neighbors emitted per query
#define KK 33                   // need the 33rd-smallest (rank index 32)
#define SPLITS_BASE (NQ * KNB)  // 524288
#define CAP 512                 // LDS candidate pool per query
#define NRR (CAP / 64)          // 8 strided regs per lane
#define NWQ 2                   // queries (waves) per block
#define G 48
#define G3 (G*G*G)              // 110592 cells
#define SCB ((G3 + 1023) / 1024) // 108 scan blocks (1024 threads each)
#define FINF (__int_as_float(0x7f800000))

// Exact replication of reference arithmetic (same as passing R1-R10 kernels):
//   q2 = (qx*qx + qy*qy) + qz*qz ; d2 likewise (recomputed exactly per candidate)
//   dot = fma(qz,z, fma(qy,y, qx*x)) ; sq = (q2+d2) - (dot+dot)
//   key = fmaxf(sq,0) ; k = sqrtf(33rd smallest key) ; accept via ulp cut probe

// ---- wave helpers ----
template<int BITS>
__device__ __forceinline__ int wave_sum_small(int v) {
    int tot = 0;
    #pragma unroll
    for (int b = 0; b < BITS; ++b)
        tot += (int)__popcll(__ballot((v >> b) & 1)) << b;
    return tot;
}
__device__ __forceinline__ float wave_max_f(float v) {
    #pragma unroll
    for (int s = 1; s < 64; s <<= 1) v = fmaxf(v, __shfl_xor(v, s, 64));
    return v;
}
__device__ __forceinline__ int wave_excl_prefix(int v, int lane) {
    int x = v;
    #pragma unroll
    for (int s = 1; s < 64; s <<= 1) {
        const int y = __shfl_up(x, s, 64);
        if (lane >= s) x += y;
    }
    return x - v;
}
__device__ __forceinline__ int iclamp(int v, int lo, int hi) {
    return v < lo ? lo : (v > hi ? hi : v);
}
__device__ __forceinline__ u32 fenc(float f) {
    const u32 u = __float_as_uint(f);
    return (u & 0x80000000u) ? ~u : (u | 0x80000000u);
}
__device__ __forceinline__ float fdec(u32 e) {
    const u32 u = (e & 0x80000000u) ? (e & 0x7fffffffu) : ~e;
    return __uint_as_float(u);
}

// min float f with #{r <= f} >= rank over the wave's strided regs (pads FINF). (R4-proven)
__device__ __forceinline__ float bisect_rank8(const float (&r)[NRR], int rank) {
    u32 lo = 0u, hi = 0x7f800000u;
    #pragma unroll 1
    while (lo < hi) {
        const u32 mid = (lo + hi) >> 1;
        const float pv = __uint_as_float(mid);
        int c = 0;
        #pragma unroll
        for (int j = 0; j < NRR; ++j) c += (r[j] <= pv) ? 1 : 0;
        const int tot = wave_sum_small<4>(c);
        if (tot >= rank) hi = mid; else lo = mid + 1;
    }
    return __uint_as_float(hi);
}

// 128-element bitonic sort across the wave, 2 regs/lane (R10-validated).
__device__ __forceinline__ void bitonic128(float& v0, float& v1, int lane) {
    #pragma unroll
    for (int k = 2; k <= 128; k <<= 1) {
        #pragma unroll
        for (int j = k >> 1; j >= 1; j >>= 1) {
            if (j >= 64) {
                const float a = fminf(v0, v1), b = fmaxf(v0, v1);
                v0 = a; v1 = b;
            } else {
                const float o0 = __shfl_xor(v0, j, 64);
                const float o1 = __shfl_xor(v1, j, 64);
                const bool bj = ((lane & j) == 0);
                const bool up0 = (k == 128) ? true : ((lane & k) == 0);
                const bool up1 = (k == 128) ? true : ((k == 64) ? false : ((lane & k) == 0));
                v0 = (bj == up0) ? fminf(v0, o0) : fmaxf(v0, o0);
                v1 = (bj == up1) ? fminf(v1, o1) : fmaxf(v1, o1);
            }
        }
    }
}

// Cheap prune (R4-proven): keep key <= M where M = wave_max(lane minima) >= pool 33rd.
__device__ __forceinline__ void pool_prune(float* kp, u32* ip, int& cnt, float& Tk,
                                           int lane, u64 lt) {
    float m = FINF;
    #pragma unroll 1
    for (int j = lane; j < cnt; j += 64) m = fminf(m, kp[j]);
    const float M = wave_max_f(m);
    int nc = 0;
    #pragma unroll 1
    for (int j0 = 0; j0 < cnt; j0 += 64) {
        const int j = j0 + lane;
        const bool val = j < cnt;
        float k = FINF; u32 id = 0;
        if (val) { k = kp[j]; id = ip[j]; }
        const bool keep = val && (k <= M);
        const u64 mask = __ballot(keep);
        if (keep) {
            const int s = nc + (int)__popcll(mask & lt);
            kp[s] = k; ip[s] = id;
        }
        nc += (int)__popcll(mask);
    }
    cnt = nc; Tk = M;
}

// Degenerate-tie path (R4-proven): keep key < v (v = exact 64th) plus <= 64 copies == v.
__device__ __forceinline__ void pool_hard_prune(float* kp, u32* ip, int& cnt,
                                                int lane, u64 lt) {
    float r[NRR];
    #pragma unroll
    for (int j = 0; j < NRR; ++j) {
        const int s = j * 64 + lane;
        r[j] = (s < cnt) ? kp[s] : FINF;
    }
    const float v = bisect_rank8(r, 64);
    int nc = 0, eqs = 0;
    #pragma unroll 1
    for (int j0 = 0; j0 < cnt; j0 += 64) {
        const int j = j0 + lane;
        const bool val = j < cnt;
        float k = FINF; u32 id = 0;
        if (val) { k = kp[j]; id = ip[j]; }
        const bool lt_v = val && (k < v);
        const bool eq_v = val && (k == v);
        const u64 mlt = __ballot(lt_v);
        const u64 meq = __ballot(eq_v);
        const int poplt = (int)__popcll(mlt);
        const int popeq = (int)__popcll(meq);
        if (lt_v) { const int s = nc + (int)__popcll(mlt & lt); kp[s] = k; ip[s] = id; }
        if (eq_v) {
            const int pe = (int)__popcll(meq & lt);
            if (eqs + pe < 64) { const int s = nc + poplt + pe; kp[s] = k; ip[s] = id; }
        }
        int kept_eq = popeq;
        if (eqs + popeq > 64) kept_eq = (64 - eqs > 0) ? (64 - eqs) : 0;
        nc += poplt + kept_eq;
        eqs += popeq;
    }
    cnt = nc;
}

// bbe[0..2] = enc(min x/y/z); bbe[3..5] = enc(min of -x/-y/-z)
__device__ __forceinline__ void grid_geom(const u32* bbe, float& mnx, float& mny, float& mnz,
                                          float& hx, float& hy, float& hz) {
    mnx = fdec(bbe[0]); mny = fdec(bbe[1]); mnz = fdec(bbe[2]);
    const float mxx = -fdec(bbe[3]), mxy = -fdec(bbe[4]), mxz = -fdec(bbe[5]);
    hx = fmaxf((mxx - mnx) * (1.0f / G), 1e-20f);
    hy = fmaxf((mxy - mny) * (1.0f / G), 1e-20f);
    hz = fmaxf((mxz - mnz) * (1.0f / G), 1e-20f);
}

__device__ __forceinline__ u32 cell_of(const u32* bbe, float x, float y, float z) {
    float mnx, mny, mnz, hx, hy, hz;
    grid_geom(bbe, mnx, mny, mnz, hx, hy, hz);
    const int cx = iclamp((int)((x - mnx) / hx), 0, G-1);
    const int cy = iclamp((int)((y - mny) / hy), 0, G-1);
    const int cz = iclamp((int)((z - mnz) / hz), 0, G-1);
    return (u32)((cz * G + cy) * G + cx);
}

// ---------- grid build (R9-proven; grid.sync ~20us/sync per R8 — avoided) ----------
__global__ __launch_bounds__(256) void bbox_kernel(const float* __restrict__ data,
                                                   u32* __restrict__ bbe,
                                                   u32* __restrict__ hist) {
    const int i = blockIdx.x * 256 + threadIdx.x;
    for (int h = i; h < G3; h += ND) hist[h] = 0u;
    const int lane = threadIdx.x & 63;
    const float x = data[3*i], y = data[3*i+1], z = data[3*i+2];
    float mnx = x, mny = y, mnz = z, nx = -x, ny = -y, nz = -z;
    #pragma unroll
    for (int s = 1; s < 64; s <<= 1) {
        mnx = fminf(mnx, __shfl_xor(mnx, s, 64)); nx = fminf(nx, __shfl_xor(nx, s, 64));
        mny = fminf(mny, __shfl_xor(mny, s, 64)); ny = fminf(ny, __shfl_xor(ny, s, 64));
        mnz = fminf(mnz, __shfl_xor(mnz, s, 64)); nz = fminf(nz, __shfl_xor(nz, s, 64));
    }
    if (lane == 0) {
        atomicMin(&bbe[0], fenc(mnx)); atomicMin(&bbe[1], fenc(mny)); atomicMin(&bbe[2], fenc(mnz));
        atomicMin(&bbe[3], fenc(nx));  atomicMin(&bbe[4], fenc(ny));  atomicMin(&bbe[5], fenc(nz));
    }
}

__global__ __launch_bounds__(256) void cellid_hist(const float* __restrict__ data,
                                                   const u32* __restrict__ bbe,
                                                   u32* __restrict__ hist) {
    const int i = blockIdx.x * 256 + threadIdx.x;
    atomicAdd(&hist[cell_of(bbe, data[3*i], data[3*i+1], data[3*i+2])], 1u);
}

__global__ __launch_bounds__(1024) void scan_partial(const u32* __restrict__ hist,
                                                     u32* __restrict__ cstart,
                                                     u32* __restrict__ bsum) {
    __shared__ u32 lds[1024];
    const int t = threadIdx.x;
    const int i = blockIdx.x * 1024 + t;
    const u32 v = (i < G3) ? hist[i] : 0u;
    lds[t] = v;
    __syncthreads();
    u32 x = v;
    for (int off = 1; off < 1024; off *= 2) {
        const u32 add = (t >= off) ? lds[t - off] : 0u;
        __syncthreads();
        x += add; lds[t] = x;
        __syncthreads();
    }
    if (i < G3) cstart[i] = x - v;
    if (t == 1023) bsum[blockIdx.x] = x;
}

__global__ __launch_bounds__(1024) void scan_add(u32* __restrict__ cstart,
                                                 u32* __restrict__ cursor,
                                                 const u32* __restrict__ bsum) {
    __shared__ u32 lds[1024];
    const int t = threadIdx.x;
    const u32 bv = (t < SCB) ? bsum[t] : 0u;
    lds[t] = bv;
    __syncthreads();
    u32 y = bv;
    for (int off = 1; off < 1024; off *= 2) {
        const u32 add = (t >= off) ? lds[t - off] : 0u;
        __syncthreads();
        y += add; lds[t] = y;
        __syncthreads();
    }
    const u32 excl = lds[blockIdx.x] - bsum[blockIdx.x];
    __syncthreads();
    const int i = blockIdx.x * 1024 + t;
    if (i < G3) {
        const u32 val = cstart[i] + excl;
        cstart[i] = val; cursor[i] = val;
    }
    if (i == 0) cstart[G3] = (u32)ND;
}

__global__ __launch_bounds__(256) void scatter(const float* __restrict__ data,
                                               const u32* __restrict__ bbe,
                                               u32* __restrict__ cursor,
                                               float4* __restrict__ pts) {
    const int i = blockIdx.x * 256 + threadIdx.x;
    const float x = data[3*i], y = data[3*i+1], z = data[3*i+2];
    const u32 pos = atomicAdd(&cursor[cell_of(bbe, x, y, z)], 1u);
    pts[pos] = make_float4(x, y, z, __uint_as_float((u32)i));
}

// ---------- main query kernel: one wave per query (R9 structure + R10 select) ----------
__global__ __launch_bounds__(64 * NWQ) void knn_grid(const float4* __restrict__ pts,
                                                     const u32* __restrict__ cstart,
                                                     const float* __restrict__ queries,
                                                     const u32* __restrict__ bbe,
                                                     int* __restrict__ out_nb,
                                                     int* __restrict__ splits) {
    __shared__ float keyP[NWQ][CAP];
    __shared__ u32   idxP[NWQ][CAP];
    __shared__ int   accI[NWQ][KNB];

    const int lane = threadIdx.x & 63;
    const int wid  = threadIdx.x >> 6;
    const int q = blockIdx.x * NWQ + wid;
    const u64 lt = (1ull << lane) - 1ull;
    float* kp = keyP[wid];
    u32*   ip = idxP[wid];

    const float qx = queries[3*q], qy = queries[3*q+1], qz = queries[3*q+2];
    const float q2 = __fadd_rn(__fadd_rn(__fmul_rn(qx,qx), __fmul_rn(qy,qy)), __fmul_rn(qz,qz));

    float mnx, mny, mnz, hx, hy, hz;
    grid_geom(bbe, mnx, mny, mnz, hx, hy, hz);
    const float hmin = fminf(hx, fminf(hy, hz));
    const int cx = iclamp((int)((qx - mnx) / hx), 0, G-1);
    const int cy = iclamp((int)((qy - mny) / hy), 0, G-1);
    const int cz = iclamp((int)((qz - mnz) / hz), 0, G-1);

    float Tk = FINF;
    int cnt = 0;

    auto gather_batch = [&](int sA, int lA, int sB, int lB) {
        const int len = lA + lB;
        const int P = wave_excl_prefix(len, lane);
        const int T = __shfl(P + len, 63, 64);
        #pragma unroll 1
        for (int g0 = 0; g0 < T; g0 += 64) {
            const int pos = g0 + lane;
            const bool val = pos < T;
            int rsel = 0;
            #pragma unroll
            for (int st = 32; st >= 1; st >>= 1) {
                const int t = rsel + st;
                const int Pt = __shfl(P, t, 64);
                if (Pt <= pos) rsel = t;
            }
            const int Pr  = __shfl(P,  rsel, 64);
            const int sAr = __shfl(sA, rsel, 64);
            const int lAr = __shfl(lA, rsel, 64);
            const int sBr = __shfl(sB, rsel, 64);
            const int off = pos - Pr;
            const int pi = (off < lAr) ? (sAr + off) : (sBr + (off - lAr));
            float key = FINF; u32 oi = 0; bool acc = false;
            if (val) {
                const float4 w = pts[pi];
                oi = __float_as_uint(w.w);
                const float d2 = __fadd_rn(__fadd_rn(__fmul_rn(w.x,w.x), __fmul_rn(w.y,w.y)),
                                           __fmul_rn(w.z,w.z));
                const float dot = __fmaf_rn(qz, w.z, __fmaf_rn(qy, w.y, __fmul_rn(qx, w.x)));
                const float sq  = __fsub_rn(__fadd_rn(q2, d2), __fadd_rn(dot, dot));
                key = fmaxf(sq, 0.0f);
                acc = key <= Tk;
            }
            const u64 mask = __ballot(acc);
            if (mask) {
                if (acc) {
                    const int s = cnt + (int)__popcll(mask & lt);
                    kp[s] = key; ip[s] = oi;
                }
                cnt += (int)__popcll(mask);
                if (cnt > CAP - 64) {
                    pool_prune(kp, ip, cnt, Tk, lane, lt);
                    if (cnt > CAP - 64) pool_hard_prune(kp, ip, cnt, lane, lt);
                }
            }
        }
    };

    // exact 33rd of pool (R10-validated): prune while >128, bitonic128, bisect fallback
    auto select33 = [&]() -> float {
        int guard = 0;
        while (cnt > 128 && guard < 2) { pool_prune(kp, ip, cnt, Tk, lane, lt); ++guard; }
        if (cnt <= 128) {
            float v0 = (lane < cnt) ? kp[lane] : FINF;
            float v1 = (64 + lane < cnt) ? kp[64 + lane] : FINF;
            bitonic128(v0, v1, lane);
            return __shfl(v0, KK - 1, 64);
        }
        float r[NRR];
        #pragma unroll
        for (int j = 0; j < NRR; ++j) {
            const int s = j * 64 + lane;
            r[j] = (s < cnt) ? kp[s] : FINF;
        }
        return bisect_rank8(r, KK);
    };

    // Phase A: find cube half-width W with >= KK points (+1 steps, then doubling)
    int W = 0;
    {
        int ccount = 0;
        while (ccount < KK && W < G) {
            W = (W < 4) ? W + 1 : ((2 * W <= G) ? 2 * W : G);
            const int side = 2*W + 1, nrows = side * side;
            ccount = 0;
            for (int r0 = 0; r0 < nrows; r0 += 64) {
                const int rid = r0 + lane;
                int len = 0;
                if (rid < nrows) {
                    const int dz = rid / side - W, dy = rid % side - W;
                    const int zz = cz + dz, yy = cy + dy;
                    if (zz >= 0 && zz < G && yy >= 0 && yy < G) {
                        const int xlo = cx - W < 0 ? 0 : cx - W;
                        const int xhi = cx + W > G-1 ? G-1 : cx + W;
                        const int rb = (zz * G + yy) * G;
                        len = (int)cstart[rb + xhi + 1] - (int)cstart[rb + xlo];
                    }
                }
                ccount += wave_sum_small<6>(len < 63 ? len : 63);
            }
        }
    }

    // Phase B1: dense gather of cube-W
    {
        const int side = 2*W + 1, nrows = side * side;
        for (int r0 = 0; r0 < nrows; r0 += 64) {
            const int rid = r0 + lane;
            int sA = 0, lA = 0;
            if (rid < nrows) {
                const int dz = rid / side - W, dy = rid % side - W;
                const int zz = cz + dz, yy = cy + dy;
                if (zz >= 0 && zz < G && yy >= 0 && yy < G) {
                    const int xlo = cx - W < 0 ? 0 : cx - W;
                    const int xhi = cx + W > G-1 ? G-1 : cx + W;
                    const int rb = (zz * G + yy) * G;
                    sA = (int)cstart[rb + xlo];
                    lA = (int)cstart[rb + xhi + 1] - sA;
                }
            }
            gather_batch(sA, lA, 0, 0);
        }
    }

    const float k33b = select33();          // exact 33rd of cube-W multiset

    // compact pool to keys <= k33b, tighten Tk
    {
        int nc = 0;
        #pragma unroll 1
        for (int j0 = 0; j0 < cnt; j0 += 64) {
            const int j = j0 + lane;
            const bool val = j < cnt;
            float k = FINF; u32 id = 0;
            if (val) { k = kp[j]; id = ip[j]; }
            const bool keep = val && (k <= k33b);
            const u64 mask = __ballot(keep);
            if (keep) {
                const int s = nc + (int)__popcll(mask & lt);
                kp[s] = k; ip[s] = id;
            }
            nc += (int)__popcll(mask);
        }
        cnt = nc; Tk = k33b;
    }

    // Phase B2: ring gather (ball minus cube) if ball(R2m) escapes cube-W
    const float R2m = __fmaf_rn(k33b, 1.0002f, 1e-3f);
    if (!(R2m < (float)W * (float)W * hmin * hmin)) {
        const float Rm = sqrtf(R2m);
        const int Dz = (int)fminf(floorf(Rm / hz) + 1.0f, (float)G);
        const int Dy = (int)fminf(floorf(Rm / hy) + 1.0f, (float)G);
        const int sidey = 2*Dy + 1;
        const int nrows = (2*Dz + 1) * sidey;
        for (int r0 = 0; r0 < nrows; r0 += 64) {
            const int rid = r0 + lane;
            int sA = 0, lA = 0, sB = 0, lB = 0;
            if (rid < nrows) {
                const int dz = rid / sidey - Dz;
                const int dy = rid % sidey - Dy;
                const int zz = cz + dz, yy = cy + dy;
                if (zz >= 0 && zz < G && yy >= 0 && yy < G) {
                    const int adz = dz < 0 ? -dz : dz;
                    const int ady = dy < 0 ? -dy : dy;
                    const float mz = (adz >= 1) ? (float)(adz - 1) * hz : 0.0f;
                    const float my = (ady >= 1) ? (float)(ady - 1) * hy : 0.0f;
                    const float rowmin2 = mz*mz + my*my;
                    if (rowmin2 <= R2m) {
                        const int dxr = (int)fminf(floorf(sqrtf(R2m - rowmin2) / hx) + 1.0f, (float)G);
                        const int xlo = cx - dxr < 0 ? 0 : cx - dxr;
                        const int xhi = cx + dxr > G-1 ? G-1 : cx + dxr;
                        if (xlo <= xhi) {
                            const int rb = (zz * G + yy) * G;
                            if (adz <= W && ady <= W) {
                                const int xhiA = (cx - W - 1 < xhi) ? cx - W - 1 : xhi;
                                const int xloB = (cx + W + 1 > xlo) ? cx + W + 1 : xlo;
                                if (xlo <= xhiA) {
                                    sA = (int)cstart[rb + xlo];
                                    lA = (int)cstart[rb + xhiA + 1] - sA;
                                }
                                if (xloB <= xhi) {
                                    sB = (int)cstart[rb + xloB];
                                    lB = (int)cstart[rb + xhi + 1] - sB;
                                }
                            } else {
                                sA = (int)cstart[rb + xlo];
                                lA = (int)cstart[rb + xhi + 1] - sA;
                            }
                        }
                    }
                }
            }
            gather_batch(sA, lA, sB, lB);
        }
    }

    const float k33 = select33();           // exact global 33rd

    // sqrt-domain cut (R4-proven)
    const float kd = sqrtf(k33);
    float cut;
    if (!(kd > 0.0f)) {
        cut = -1.0f;
    } else {
        int bi = __float_as_int(__fmul_rn(kd, kd));
        #pragma unroll 1
        for (int s = 0; s < 8; ++s) {
            if (bi > 0 && sqrtf(__int_as_float(bi - 1)) >= kd) --bi; else break;
        }
        #pragma unroll 1
        for (int s = 0; s < 8; ++s) {
            if (sqrtf(__int_as_float(bi)) < kd) ++bi; else break;
        }
        cut = __int_as_float(bi);
    }

    // filter pool by key < cut, compact to accI
    int c = 0;
    #pragma unroll 1
    for (int j0 = 0; j0 < cnt; j0 += 64) {
        const int j = j0 + lane;
        const bool val = j < cnt;
        const float k = val ? kp[j] : FINF;
        const bool keep = val && (k < cut);
        const u64 mask = __ballot(keep);
        if (keep) {
            const int s = c + (int)__popcll(mask & lt);
            if (s < KNB) accI[wid][s] = (int)ip[j];
        }
        c += (int)__popcll(mask);
    }
    if (c > KNB) c = KNB;

    // ranking sort by index ascending + padded row write
    if (lane < KNB) {
        if (lane < c) {
            const int my = accI[wid][lane];
            int rank = 0;
            #pragma unroll 1
            for (int j = 0; j < KNB; ++j)
                if (j < c) rank += (accI[wid][j] < my) ? 1 : 0;
            out_nb[(size_t)q * KNB + rank] = my;
        } else {
            out_nb[(size_t)q * KNB + lane] = ND;
        }
    }
    if (lane == 0) splits[1 + q] = c;
}

// --- fallback (ws too small): direct per-thread scan (correct, slow) ---
__global__ __launch_bounds__(256) void knn_direct_kernel(const float* __restrict__ data,
                                                         const float* __restrict__ queries,
                                                         int* __restrict__ out_nb,
                                                         int* __restrict__ splits) {
    __shared__ float4 tile[1024];
    const int q = blockIdx.x * 256 + threadIdx.x;
    const float qx = queries[3*q], qy = queries[3*q+1], qz = queries[3*q+2];
    const float q2 = __fadd_rn(__fadd_rn(__fmul_rn(qx,qx), __fmul_rn(qy,qy)), __fmul_rn(qz,qz));
    float arrk[KK]; int arri[KK];
    for (int j = 0; j < KK; ++j) { arrk[j] = FINF; arri[j] = ND; }
    float cur_maxk = FINF;
    for (int t0 = 0; t0 < ND; t0 += 1024) {
        for (int p = threadIdx.x; p < 1024; p += 256) {
            const int g = t0 + p;
            const float x = data[3*g], y = data[3*g+1], z = data[3*g+2];
            const float d2 = __fadd_rn(__fadd_rn(__fmul_rn(x,x), __fmul_rn(y,y)), __fmul_rn(z,z));
            tile[p] = make_float4(x, y, z, d2);
        }
        __syncthreads();
        for (int p = 0; p < 1024; ++p) {
            const float4 dp = tile[p];
            const float dot = __fmaf_rn(qz, dp.z, __fmaf_rn(qy, dp.y, __fmul_rn(qx, dp.x)));
            const float sq  = __fsub_rn(__fadd_rn(q2, dp.w), __fadd_rn(dot, dot));
            const float key = fmaxf(sq, 0.0f);
            if (key < cur_maxk) {
                int mp = 0; float m = -1.0f;
                for (int j = 0; j < KK; ++j) if (arrk[j] > m) { m = arrk[j]; mp = j; }
                arrk[mp] = key; arri[mp] = t0 + p;
                m = -1.0f;
                for (int j = 0; j < KK; ++j) if (arrk[j] > m) m = arrk[j];
                cur_maxk = m;
            }
        }
        __syncthreads();
    }
    const float kdist = sqrtf(cur_maxk);
    int acc[KNB]; int c = 0;
    for (int j = 0; j < KK; ++j) {
        const float d = sqrtf(arrk[j]);
        if (d < kdist && c < KNB) acc[c++] = arri[j];
    }
    for (int a = 1; a < c; ++a) {
        const int v = acc[a]; int j = a;
        while (j > 0 && acc[j-1] > v) { acc[j] = acc[j-1]; --j; }
        acc[j] = v;
    }
    int* row = out_nb + (size_t)q * KNB;
    for (int j = 0; j < KNB; ++j) row[j] = (j < c) ? acc[j] : ND;
    splits[1 + q] = c;
}

// --- splits: in-place scan of counts (single block) ---
__global__ __launch_bounds__(1024) void splits_scan_kernel(int* __restrict__ splits) {
    __shared__ int lds[1024];
    const int t = threadIdx.x;
    int v[16]; int s = 0;
    #pragma unroll
    for (int j = 0; j < 16; ++j) { v[j] = splits[1 + t*16 + j]; s += v[j]; }
    lds[t] = s;
    __syncthreads();
    for (int off = 1; off < 1024; off *= 2) {
        const int add = (t >= off) ? lds[t - off] : 0;
        __syncthreads();
        lds[t] += add;
        __syncthreads();
    }
    int run = lds[t] - s;
    #pragma unroll
    for (int j = 0; j < 16; ++j) { run += v[j]; splits[1 + t*16 + j] = run; }
    if (t == 0) splits[0] = 0;
}

extern "C" void kernel_launch(void* const* d_in, const int* in_sizes, int n_in,
                              void* d_out, int out_size, void* d_ws, size_t ws_size,
                              hipStream_t stream) {
    const float* data    = (const float*)d_in[0];
    const float* queries = (const float*)d_in[1];
    int* out    = (int*)d_out;
    int* splits = out + SPLITS_BASE;

    const size_t bb_off     = 0;
    const size_t hist_off   = 64;
    const size_t cstart_off = hist_off + (size_t)G3 * 4;
    const size_t cursor_off = cstart_off + (size_t)(G3 + 1) * 4;
    const size_t bsum_off   = cursor_off + (size_t)G3 * 4;
    size_t pts_off          = bsum_off + 1024 * 4;
    pts_off = (pts_off + 255) & ~(size_t)255;
    const size_t need       = pts_off + (size_t)ND * 16;           // ~1.6 MB

    if (ws_size >= need) {
        u32*    bbe    = (u32*)((char*)d_ws + bb_off);
        u32*    hist   = (u32*)((char*)d_ws + hist_off);
        u32*    cstart = (u32*)((char*)d_ws + cstart_off);
        u32*    cursor = (u32*)((char*)d_ws + cursor_off);
        u32*    bsum   = (u32*)((char*)d_ws + bsum_off);
        float4* pts    = (float4*)((char*)d_ws + pts_off);

        hipMemsetAsync(bbe, 0xFF, 24, stream);
        hipLaunchKernelGGL(bbox_kernel, dim3(ND / 256), dim3(256), 0, stream, data, bbe, hist);
        hipLaunchKernelGGL(cellid_hist, dim3(ND / 256), dim3(256), 0, stream, data, bbe, hist);
        hipLaunchKernelGGL(scan_partial, dim3(SCB), dim3(1024), 0, stream, hist, cstart, bsum);
        hipLaunchKernelGGL(scan_add, dim3(SCB), dim3(1024), 0, stream, cstart, cursor, bsum);
        hipLaunchKernelGGL(scatter, dim3(ND / 256), dim3(256), 0, stream, data, bbe, cursor, pts);
        hipLaunchKernelGGL(knn_grid, dim3(NQ / NWQ), dim3(64 * NWQ), 0, stream,
                           pts, cstart, queries, bbe, out, splits);
    } else {
        hipLaunchKernelGGL(knn_direct_kernel, dim3(NQ / 256), dim3(256), 0, stream,
                           data, queries, out, splits);
    }
    hipLaunchKernelGGL(splits_scan_kernel, dim3(1), dim3(1024), 0, stream, splits);
}

// Round 12
// 109.602 us; speedup vs baseline: 1.1429x; 1.1429x over previous
//
#include <hip/hip_runtime.h>
#include <stdint.h>

typedef unsigned long long u64;
typedef unsigned int u32;

#define NQ 16384
#define ND 16384
#define KNB 32                  // neighbors emitted per query
#define KK 33                   // need the 33rd-smallest (rank index 32)
#define SPLITS_BASE (NQ * KNB)  // 524288
#define CAP 512                 // LDS candidate pool per query
#define NRR (CAP / 64)          // 8 strided regs per lane
#define NWQ 2                   // queries (waves) per block
#define G 36
#define G3 (G*G*G)              // 46656 cells
#define SCB ((G3 + 255) / 256)  // 183 scan blocks
#define FINF (__int_as_float(0x7f800000))

// Exact replication of reference arithmetic (same as passing R1-R11 kernels):
//   q2 = (qx*qx + qy*qy) + qz*qz ; d2 likewise (recomputed exactly per candidate)
//   dot = fma(qz,z, fma(qy,y, qx*x)) ; sq = (q2+d2) - (dot+dot)
//   key = fmaxf(sq,0) ; k = sqrtf(33rd smallest key) ; accept via ulp cut probe

// ---- wave helpers ----
template<int BITS>
__device__ __forceinline__ int wave_sum_small(int v) {
    int tot = 0;
    #pragma unroll
    for (int b = 0; b < BITS; ++b)
        tot += (int)__popcll(__ballot((v >> b) & 1)) << b;
    return tot;
}
__device__ __forceinline__ float wave_max_f(float v) {
    #pragma unroll
    for (int s = 1; s < 64; s <<= 1) v = fmaxf(v, __shfl_xor(v, s, 64));
    return v;
}
__device__ __forceinline__ int wave_excl_prefix(int v, int lane) {
    int x = v;
    #pragma unroll
    for (int s = 1; s < 64; s <<= 1) {
        const int y = __shfl_up(x, s, 64);
        if (lane >= s) x += y;
    }
    return x - v;
}
__device__ __forceinline__ int iclamp(int v, int lo, int hi) {
    return v < lo ? lo : (v > hi ? hi : v);
}
__device__ __forceinline__ u32 fenc(float f) {
    const u32 u = __float_as_uint(f);
    return (u & 0x80000000u) ? ~u : (u | 0x80000000u);
}
__device__ __forceinline__ float fdec(u32 e) {
    const u32 u = (e & 0x80000000u) ? (e & 0x7fffffffu) : ~e;
    return __uint_as_float(u);
}

// min float f with #{r <= f} >= rank over the wave's strided regs (pads FINF). (R4-proven)
__device__ __forceinline__ float bisect_rank8(const float (&r)[NRR], int rank) {
    u32 lo = 0u, hi = 0x7f800000u;
    #pragma unroll 1
    while (lo < hi) {
        const u32 mid = (lo + hi) >> 1;
        const float pv = __uint_as_float(mid);
        int c = 0;
        #pragma unroll
        for (int j = 0; j < NRR; ++j) c += (r[j] <= pv) ? 1 : 0;
        const int tot = wave_sum_small<4>(c);
        if (tot >= rank) hi = mid; else lo = mid + 1;
    }
    return __uint_as_float(hi);
}

// 128-element bitonic sort across the wave, 2 regs/lane (validated R10/R11).
__device__ __forceinline__ void bitonic128(float& v0, float& v1, int lane) {
    #pragma unroll
    for (int k = 2; k <= 128; k <<= 1) {
        #pragma unroll
        for (int j = k >> 1; j >= 1; j >>= 1) {
            if (j >= 64) {
                const float a = fminf(v0, v1), b = fmaxf(v0, v1);
                v0 = a; v1 = b;
            } else {
                const float o0 = __shfl_xor(v0, j, 64);
                const float o1 = __shfl_xor(v1, j, 64);
                const bool bj = ((lane & j) == 0);
                const bool up0 = (k == 128) ? true : ((lane & k) == 0);
                const bool up1 = (k == 128) ? true : ((k == 64) ? false : ((lane & k) == 0));
                v0 = (bj == up0) ? fminf(v0, o0) : fmaxf(v0, o0);
                v1 = (bj == up1) ? fminf(v1, o1) : fmaxf(v1, o1);
            }
        }
    }
}

// Cheap prune (R4-proven): keep key <= M where M = wave_max(lane minima) >= pool 33rd.
__device__ __forceinline__ void pool_prune(float* kp, u32* ip, int& cnt, float& Tk,
                                           int lane, u64 lt) {
    float m = FINF;
    #pragma unroll 1
    for (int j = lane; j < cnt; j += 64) m = fminf(m, kp[j]);
    const float M = wave_max_f(m);
    int nc = 0;
    #pragma unroll 1
    for (int j0 = 0; j0 < cnt; j0 += 64) {
        const int j = j0 + lane;
        const bool val = j < cnt;
        float k = FINF; u32 id = 0;
        if (val) { k = kp[j]; id = ip[j]; }
        const bool keep = val && (k <= M);
        const u64 mask = __ballot(keep);
        if (keep) {
            const int s = nc + (int)__popcll(mask & lt);
            kp[s] = k; ip[s] = id;
        }
        nc += (int)__popcll(mask);
    }
    cnt = nc; Tk = M;
}

// Degenerate-tie path (R4-proven): keep key < v (v = exact 64th) plus <= 64 copies == v.
__device__ __forceinline__ void pool_hard_prune(float* kp, u32* ip, int& cnt,
                                                int lane, u64 lt) {
    float r[NRR];
    #pragma unroll
    for (int j = 0; j < NRR; ++j) {
        const int s = j * 64 + lane;
        r[j] = (s < cnt) ? kp[s] : FINF;
    }
    const float v = bisect_rank8(r, 64);
    int nc = 0, eqs = 0;
    #pragma unroll 1
    for (int j0 = 0; j0 < cnt; j0 += 64) {
        const int j = j0 + lane;
        const bool val = j < cnt;
        float k = FINF; u32 id = 0;
        if (val) { k = kp[j]; id = ip[j]; }
        const bool lt_v = val && (k < v);
        const bool eq_v = val && (k == v);
        const u64 mlt = __ballot(lt_v);
        const u64 meq = __ballot(eq_v);
        const int poplt = (int)__popcll(mlt);
        const int popeq = (int)__popcll(meq);
        if (lt_v) { const int s = nc + (int)__popcll(mlt & lt); kp[s] = k; ip[s] = id; }
        if (eq_v) {
            const int pe = (int)__popcll(meq & lt);
            if (eqs + pe < 64) { const int s = nc + poplt + pe; kp[s] = k; ip[s] = id; }
        }
        int kept_eq = popeq;
        if (eqs + popeq > 64) kept_eq = (64 - eqs > 0) ? (64 - eqs) : 0;
        nc += poplt + kept_eq;
        eqs += popeq;
    }
    cnt = nc;
}

// bbe[0..2] = enc(min x/y/z); bbe[3..5] = enc(min of -x/-y/-z)
__device__ __forceinline__ void grid_geom(const u32* bbe, float& mnx, float& mny, float& mnz,
                                          float& hx, float& hy, float& hz) {
    mnx = fdec(bbe[0]); mny = fdec(bbe[1]); mnz = fdec(bbe[2]);
    const float mxx = -fdec(bbe[3]), mxy = -fdec(bbe[4]), mxz = -fdec(bbe[5]);
    hx = fmaxf((mxx - mnx) * (1.0f / G), 1e-20f);
    hy = fmaxf((mxy - mny) * (1.0f / G), 1e-20f);
    hz = fmaxf((mxz - mnz) * (1.0f / G), 1e-20f);
}

__device__ __forceinline__ u32 cell_of(const u32* bbe, float x, float y, float z) {
    float mnx, mny, mnz, hx, hy, hz;
    grid_geom(bbe, mnx, mny, mnz, hx, hy, hz);
    const int cx = iclamp((int)((x - mnx) / hx), 0, G-1);
    const int cy = iclamp((int)((y - mny) / hy), 0, G-1);
    const int cz = iclamp((int)((z - mnz) / hz), 0, G-1);
    return (u32)((cz * G + cy) * G + cx);
}

// ---------- grid build (R9-proven; grid.sync ~20us/sync per R8 — avoided) ----------
__global__ __launch_bounds__(256) void bbox_kernel(const float* __restrict__ data,
                                                   u32* __restrict__ bbe,
                                                   u32* __restrict__ hist) {
    const int i = blockIdx.x * 256 + threadIdx.x;
    for (int h = i; h < G3; h += ND) hist[h] = 0u;
    const int lane = threadIdx.x & 63;
    const float x = data[3*i], y = data[3*i+1], z = data[3*i+2];
    float mnx = x, mny = y, mnz = z, nx = -x, ny = -y, nz = -z;
    #pragma unroll
    for (int s = 1; s < 64; s <<= 1) {
        mnx = fminf(mnx, __shfl_xor(mnx, s, 64)); nx = fminf(nx, __shfl_xor(nx, s, 64));
        mny = fminf(mny, __shfl_xor(mny, s, 64)); ny = fminf(ny, __shfl_xor(ny, s, 64));
        mnz = fminf(mnz, __shfl_xor(mnz, s, 64)); nz = fminf(nz, __shfl_xor(nz, s, 64));
    }
    if (lane == 0) {
        atomicMin(&bbe[0], fenc(mnx)); atomicMin(&bbe[1], fenc(mny)); atomicMin(&bbe[2], fenc(mnz));
        atomicMin(&bbe[3], fenc(nx));  atomicMin(&bbe[4], fenc(ny));  atomicMin(&bbe[5], fenc(nz));
    }
}

__global__ __launch_bounds__(256) void cellid_hist(const float* __restrict__ data,
                                                   const u32* __restrict__ bbe,
                                                   u32* __restrict__ hist) {
    const int i = blockIdx.x * 256 + threadIdx.x;
    atomicAdd(&hist[cell_of(bbe, data[3*i], data[3*i+1], data[3*i+2])], 1u);
}

__global__ __launch_bounds__(256) void scan_partial(const u32* __restrict__ hist,
                                                    u32* __restrict__ cstart,
                                                    u32* __restrict__ bsum) {
    __shared__ u32 lds[256];
    const int t = threadIdx.x;
    const int i = blockIdx.x * 256 + t;
    const u32 v = (i < G3) ? hist[i] : 0u;
    lds[t] = v;
    __syncthreads();
    u32 x = v;
    for (int off = 1; off < 256; off *= 2) {
        const u32 add = (t >= off) ? lds[t - off] : 0u;
        __syncthreads();
        x += add; lds[t] = x;
        __syncthreads();
    }
    if (i < G3) cstart[i] = x - v;
    if (t == 255) bsum[blockIdx.x] = x;
}

__global__ __launch_bounds__(256) void scan_add(u32* __restrict__ cstart,
                                                u32* __restrict__ cursor,
                                                const u32* __restrict__ bsum) {
    __shared__ u32 lds[256];
    const int t = threadIdx.x;
    const u32 bv = (t < SCB) ? bsum[t] : 0u;
    lds[t] = bv;
    __syncthreads();
    u32 y = bv;
    for (int off = 1; off < 256; off *= 2) {
        const u32 add = (t >= off) ? lds[t - off] : 0u;
        __syncthreads();
        y += add; lds[t] = y;
        __syncthreads();
    }
    const u32 excl = lds[blockIdx.x] - ((blockIdx.x < SCB) ? bsum[blockIdx.x] : 0u);
    __syncthreads();
    const int i = blockIdx.x * 256 + t;
    if (i < G3) {
        const u32 val = cstart[i] + excl;
        cstart[i] = val; cursor[i] = val;
    }
    if (i == 0) cstart[G3] = (u32)ND;
}

__global__ __launch_bounds__(256) void scatter(const float* __restrict__ data,
                                               const u32* __restrict__ bbe,
                                               u32* __restrict__ cursor,
                                               float4* __restrict__ pts) {
    const int i = blockIdx.x * 256 + threadIdx.x;
    const float x = data[3*i], y = data[3*i+1], z = data[3*i+2];
    const u32 pos = atomicAdd(&cursor[cell_of(bbe, x, y, z)], 1u);
    pts[pos] = make_float4(x, y, z, __uint_as_float((u32)i));
}

// ---------- main query kernel: one wave per query (R9 structure; select swapped) ----------
__global__ __launch_bounds__(64 * NWQ) void knn_grid(const float4* __restrict__ pts,
                                                     const u32* __restrict__ cstart,
                                                     const float* __restrict__ queries,
                                                     const u32* __restrict__ bbe,
                                                     int* __restrict__ out_nb,
                                                     int* __restrict__ splits) {
    __shared__ float keyP[NWQ][CAP];
    __shared__ u32   idxP[NWQ][CAP];
    __shared__ int   accI[NWQ][KNB];

    const int lane = threadIdx.x & 63;
    const int wid  = threadIdx.x >> 6;
    const int q = blockIdx.x * NWQ + wid;
    const u64 lt = (1ull << lane) - 1ull;
    float* kp = keyP[wid];
    u32*   ip = idxP[wid];

    const float qx = queries[3*q], qy = queries[3*q+1], qz = queries[3*q+2];
    const float q2 = __fadd_rn(__fadd_rn(__fmul_rn(qx,qx), __fmul_rn(qy,qy)), __fmul_rn(qz,qz));

    float mnx, mny, mnz, hx, hy, hz;
    grid_geom(bbe, mnx, mny, mnz, hx, hy, hz);
    const float hmin = fminf(hx, fminf(hy, hz));
    const int cx = iclamp((int)((qx - mnx) / hx), 0, G-1);
    const int cy = iclamp((int)((qy - mny) / hy), 0, G-1);
    const int cz = iclamp((int)((qz - mnz) / hz), 0, G-1);

    float Tk = FINF;
    int cnt = 0;

    auto gather_batch = [&](int sA, int lA, int sB, int lB) {
        const int len = lA + lB;
        const int P = wave_excl_prefix(len, lane);
        const int T = __shfl(P + len, 63, 64);
        #pragma unroll 1
        for (int g0 = 0; g0 < T; g0 += 64) {
            const int pos = g0 + lane;
            const bool val = pos < T;
            int rsel = 0;
            #pragma unroll
            for (int st = 32; st >= 1; st >>= 1) {
                const int t = rsel + st;
                const int Pt = __shfl(P, t, 64);
                if (Pt <= pos) rsel = t;
            }
            const int Pr  = __shfl(P,  rsel, 64);
            const int sAr = __shfl(sA, rsel, 64);
            const int lAr = __shfl(lA, rsel, 64);
            const int sBr = __shfl(sB, rsel, 64);
            const int off = pos - Pr;
            const int pi = (off < lAr) ? (sAr + off) : (sBr + (off - lAr));
            float key = FINF; u32 oi = 0; bool acc = false;
            if (val) {
                const float4 w = pts[pi];
                oi = __float_as_uint(w.w);
                const float d2 = __fadd_rn(__fadd_rn(__fmul_rn(w.x,w.x), __fmul_rn(w.y,w.y)),
                                           __fmul_rn(w.z,w.z));
                const float dot = __fmaf_rn(qz, w.z, __fmaf_rn(qy, w.y, __fmul_rn(qx, w.x)));
                const float sq  = __fsub_rn(__fadd_rn(q2, d2), __fadd_rn(dot, dot));
                key = fmaxf(sq, 0.0f);
                acc = key <= Tk;
            }
            const u64 mask = __ballot(acc);
            if (mask) {
                if (acc) {
                    const int s = cnt + (int)__popcll(mask & lt);
                    kp[s] = key; ip[s] = oi;
                }
                cnt += (int)__popcll(mask);
                if (cnt > CAP - 64) {
                    pool_prune(kp, ip, cnt, Tk, lane, lt);
                    if (cnt > CAP - 64) pool_hard_prune(kp, ip, cnt, lane, lt);
                }
            }
        }
    };

    // exact 33rd of pool: prune while >128 (R4-proven keeps pool-33rd and all keys < cut),
    // then register bitonic128; bisect only as tie-storm fallback. (values identical to R9)
    auto select33 = [&]() -> float {
        int guard = 0;
        while (cnt > 128 && guard < 2) { pool_prune(kp, ip, cnt, Tk, lane, lt); ++guard; }
        if (cnt <= 128) {
            float v0 = (lane < cnt) ? kp[lane] : FINF;
            float v1 = (64 + lane < cnt) ? kp[64 + lane] : FINF;
            bitonic128(v0, v1, lane);
            return __shfl(v0, KK - 1, 64);
        }
        float r[NRR];
        #pragma unroll
        for (int j = 0; j < NRR; ++j) {
            const int s = j * 64 + lane;
            r[j] = (s < cnt) ? kp[s] : FINF;
        }
        return bisect_rank8(r, KK);
    };

    // Phase A: smallest cube half-width W (cells) with >= KK points (+1 escalation, R9)
    int W = 0;
    {
        int ccount = 0;
        while (ccount < KK && W < G) {
            ++W;
            const int side = 2*W + 1, nrows = side * side;
            ccount = 0;
            for (int r0 = 0; r0 < nrows; r0 += 64) {
                const int rid = r0 + lane;
                int len = 0;
                if (rid < nrows) {
                    const int dz = rid / side - W, dy = rid % side - W;
                    const int zz = cz + dz, yy = cy + dy;
                    if (zz >= 0 && zz < G && yy >= 0 && yy < G) {
                        const int xlo = cx - W < 0 ? 0 : cx - W;
                        const int xhi = cx + W > G-1 ? G-1 : cx + W;
                        const int rb = (zz * G + yy) * G;
                        len = (int)cstart[rb + xhi + 1] - (int)cstart[rb + xlo];
                    }
                }
                ccount += wave_sum_small<6>(len < 63 ? len : 63);
            }
        }
    }

    // Phase B1: dense gather of cube-W (R9)
    {
        const int side = 2*W + 1, nrows = side * side;
        for (int r0 = 0; r0 < nrows; r0 += 64) {
            const int rid = r0 + lane;
            int sA = 0, lA = 0;
            if (rid < nrows) {
                const int dz = rid / side - W, dy = rid % side - W;
                const int zz = cz + dz, yy = cy + dy;
                if (zz >= 0 && zz < G && yy >= 0 && yy < G) {
                    const int xlo = cx - W < 0 ? 0 : cx - W;
                    const int xhi = cx + W > G-1 ? G-1 : cx + W;
                    const int rb = (zz * G + yy) * G;
                    sA = (int)cstart[rb + xlo];
                    lA = (int)cstart[rb + xhi + 1] - sA;
                }
            }
            gather_batch(sA, lA, 0, 0);
        }
    }

    const float k33b = select33();          // exact 33rd of cube-W multiset

    // compact pool to keys <= k33b, tighten Tk (R9)
    {
        int nc = 0;
        #pragma unroll 1
        for (int j0 = 0; j0 < cnt; j0 += 64) {
            const int j = j0 + lane;
            const bool val = j < cnt;
            float k = FINF; u32 id = 0;
            if (val) { k = kp[j]; id = ip[j]; }
            const bool keep = val && (k <= k33b);
            const u64 mask = __ballot(keep);
            if (keep) {
                const int s = nc + (int)__popcll(mask & lt);
                kp[s] = k; ip[s] = id;
            }
            nc += (int)__popcll(mask);
        }
        cnt = nc; Tk = k33b;
    }

    // Phase B2: ring gather (ball minus cube) if ball(R2m) escapes cube-W (R9)
    const float R2m = __fmaf_rn(k33b, 1.0002f, 1e-3f);
    if (!(R2m < (float)W * (float)W * hmin * hmin)) {
        const float Rm = sqrtf(R2m);
        const int Dz = (int)fminf(floorf(Rm / hz) + 1.0f, (float)G);
        const int Dy = (int)fminf(floorf(Rm / hy) + 1.0f, (float)G);
        const int sidey = 2*Dy + 1;
        const int nrows = (2*Dz + 1) * sidey;
        for (int r0 = 0; r0 < nrows; r0 += 64) {
            const int rid = r0 + lane;
            int sA = 0, lA = 0, sB = 0, lB = 0;
            if (rid < nrows) {
                const int dz = rid / sidey - Dz;
                const int dy = rid % sidey - Dy;
                const int zz = cz + dz, yy = cy + dy;
                if (zz >= 0 && zz < G && yy >= 0 && yy < G) {
                    const int adz = dz < 0 ? -dz : dz;
                    const int ady = dy < 0 ? -dy : dy;
                    const float mz = (adz >= 1) ? (float)(adz - 1) * hz : 0.0f;
                    const float my = (ady >= 1) ? (float)(ady - 1) * hy : 0.0f;
                    const float rowmin2 = mz*mz + my*my;
                    if (rowmin2 <= R2m) {
                        const int dxr = (int)fminf(floorf(sqrtf(R2m - rowmin2) / hx) + 1.0f, (float)G);
                        const int xlo = cx - dxr < 0 ? 0 : cx - dxr;
                        const int xhi = cx + dxr > G-1 ? G-1 : cx + dxr;
                        if (xlo <= xhi) {
                            const int rb = (zz * G + yy) * G;
                            if (adz <= W && ady <= W) {
                                const int xhiA = (cx - W - 1 < xhi) ? cx - W - 1 : xhi;
                                const int xloB = (cx + W + 1 > xlo) ? cx + W + 1 : xlo;
                                if (xlo <= xhiA) {
                                    sA = (int)cstart[rb + xlo];
                                    lA = (int)cstart[rb + xhiA + 1] - sA;
                                }
                                if (xloB <= xhi) {
                                    sB = (int)cstart[rb + xloB];
                                    lB = (int)cstart[rb + xhi + 1] - sB;
                                }
                            } else {
                                sA = (int)cstart[rb + xlo];
                                lA = (int)cstart[rb + xhi + 1] - sA;
                            }
                        }
                    }
                }
            }
            gather_batch(sA, lA, sB, lB);
        }
    }

    const float k33 = select33();           // exact global 33rd

    // sqrt-domain cut (R4-proven)
    const float kd = sqrtf(k33);
    float cut;
    if (!(kd > 0.0f)) {
        cut = -1.0f;
    } else {
        int bi = __float_as_int(__fmul_rn(kd, kd));
        #pragma unroll 1
        for (int s = 0; s < 8; ++s) {
            if (bi > 0 && sqrtf(__int_as_float(bi - 1)) >= kd) --bi; else break;
        }
        #pragma unroll 1
        for (int s = 0; s < 8; ++s) {
            if (sqrtf(__int_as_float(bi)) < kd) ++bi; else break;
        }
        cut = __int_as_float(bi);
    }

    // filter pool by key < cut, compact to accI (R9)
    int c = 0;
    #pragma unroll 1
    for (int j0 = 0; j0 < cnt; j0 += 64) {
        const int j = j0 + lane;
        const bool val = j < cnt;
        const float k = val ? kp[j] : FINF;
        const bool keep = val && (k < cut);
        const u64 mask = __ballot(keep);
        if (keep) {
            const int s = c + (int)__popcll(mask & lt);
            if (s < KNB) accI[wid][s] = (int)ip[j];
        }
        c += (int)__popcll(mask);
    }
    if (c > KNB) c = KNB;

    // ranking sort by index ascending + padded row write (R9)
    if (lane < KNB) {
        if (lane < c) {
            const int my = accI[wid][lane];
            int rank = 0;
            #pragma unroll 1
            for (int j = 0; j < KNB; ++j)
                if (j < c) rank += (accI[wid][j] < my) ? 1 : 0;
            out_nb[(size_t)q * KNB + rank] = my;
        } else {
            out_nb[(size_t)q * KNB + lane] = ND;
        }
    }
    if (lane == 0) splits[1 + q] = c;
}

// --- fallback (ws too small): direct per-thread scan (correct, slow) ---
__global__ __launch_bounds__(256) void knn_direct_kernel(const float* __restrict__ data,
                                                         const float* __restrict__ queries,
                                                         int* __restrict__ out_nb,
                                                         int* __restrict__ splits) {
    __shared__ float4 tile[1024];
    const int q = blockIdx.x * 256 + threadIdx.x;
    const float qx = queries[3*q], qy = queries[3*q+1], qz = queries[3*q+2];
    const float q2 = __fadd_rn(__fadd_rn(__fmul_rn(qx,qx), __fmul_rn(qy,qy)), __fmul_rn(qz,qz));
    float arrk[KK]; int arri[KK];
    for (int j = 0; j < KK; ++j) { arrk[j] = FINF; arri[j] = ND; }
    float cur_maxk = FINF;
    for (int t0 = 0; t0 < ND; t0 += 1024) {
        for (int p = threadIdx.x; p < 1024; p += 256) {
            const int g = t0 + p;
            const float x = data[3*g], y = data[3*g+1], z = data[3*g+2];
            const float d2 = __fadd_rn(__fadd_rn(__fmul_rn(x,x), __fmul_rn(y,y)), __fmul_rn(z,z));
            tile[p] = make_float4(x, y, z, d2);
        }
        __syncthreads();
        for (int p = 0; p < 1024; ++p) {
            const float4 dp = tile[p];
            const float dot = __fmaf_rn(qz, dp.z, __fmaf_rn(qy, dp.y, __fmul_rn(qx, dp.x)));
            const float sq  = __fsub_rn(__fadd_rn(q2, dp.w), __fadd_rn(dot, dot));
            const float key = fmaxf(sq, 0.0f);
            if (key < cur_maxk) {
                int mp = 0; float m = -1.0f;
                for (int j = 0; j < KK; ++j) if (arrk[j] > m) { m = arrk[j]; mp = j; }
                arrk[mp] = key; arri[mp] = t0 + p;
                m = -1.0f;
                for (int j = 0; j < KK; ++j) if (arrk[j] > m) m = arrk[j];
                cur_maxk = m;
            }
        }
        __syncthreads();
    }
    const float kdist = sqrtf(cur_maxk);
    int acc[KNB]; int c = 0;
    for (int j = 0; j < KK; ++j) {
        const float d = sqrtf(arrk[j]);
        if (d < kdist && c < KNB) acc[c++] = arri[j];
    }
    for (int a = 1; a < c; ++a) {
        const int v = acc[a]; int j = a;
        while (j > 0 && acc[j-1] > v) { acc[j] = acc[j-1]; --j; }
        acc[j] = v;
    }
    int* row = out_nb + (size_t)q * KNB;
    for (int j = 0; j < KNB; ++j) row[j] = (j < c) ? acc[j] : ND;
    splits[1 + q] = c;
}

// --- splits: in-place scan of counts (single block) ---
__global__ __launch_bounds__(1024) void splits_scan_kernel(int* __restrict__ splits) {
    __shared__ int lds[1024];
    const int t = threadIdx.x;
    int v[16]; int s = 0;
    #pragma unroll
    for (int j = 0; j < 16; ++j) { v[j] = splits[1 + t*16 + j]; s += v[j]; }
    lds[t] = s;
    __syncthreads();
    for (int off = 1; off < 1024; off *= 2) {
        const int add = (t >= off) ? lds[t - off] : 0;
        __syncthreads();
        lds[t] += add;
        __syncthreads();
    }
    int run = lds[t] - s;
    #pragma unroll
    for (int j = 0; j < 16; ++j) { run += v[j]; splits[1 + t*16 + j] = run; }
    if (t == 0) splits[0] = 0;
}

extern "C" void kernel_launch(void* const* d_in, const int* in_sizes, int n_in,
                              void* d_out, int out_size, void* d_ws, size_t ws_size,
                              hipStream_t stream) {
    const float* data    = (const float*)d_in[0];
    const float* queries = (const float*)d_in[1];
    int* out    = (int*)d_out;
    int* splits = out + SPLITS_BASE;

    const size_t bb_off     = 0;
    const size_t hist_off   = 64;
    const size_t cstart_off = hist_off + (size_t)G3 * 4;
    const size_t cursor_off = cstart_off + (size_t)(G3 + 1) * 4;
    const size_t bsum_off   = cursor_off + (size_t)G3 * 4;
    size_t pts_off          = bsum_off + 256 * 4;
    pts_off = (pts_off + 255) & ~(size_t)255;
    const size_t need       = pts_off + (size_t)ND * 16;           // ~820 KB

    if (ws_size >= need) {
        u32*    bbe    = (u32*)((char*)d_ws + bb_off);
        u32*    hist   = (u32*)((char*)d_ws + hist_off);
        u32*    cstart = (u32*)((char*)d_ws + cstart_off);
        u32*    cursor = (u32*)((char*)d_ws + cursor_off);
        u32*    bsum   = (u32*)((char*)d_ws + bsum_off);
        float4* pts    = (float4*)((char*)d_ws + pts_off);

        hipMemsetAsync(bbe, 0xFF, 24, stream);
        hipLaunchKernelGGL(bbox_kernel, dim3(ND / 256), dim3(256), 0, stream, data, bbe, hist);
        hipLaunchKernelGGL(cellid_hist, dim3(ND / 256), dim3(256), 0, stream, data, bbe, hist);
        hipLaunchKernelGGL(scan_partial, dim3(SCB), dim3(256), 0, stream, hist, cstart, bsum);
        hipLaunchKernelGGL(scan_add, dim3(SCB), dim3(256), 0, stream, cstart, cursor, bsum);
        hipLaunchKernelGGL(scatter, dim3(ND / 256), dim3(256), 0, stream, data, bbe, cursor, pts);
        hipLaunchKernelGGL(knn_grid, dim3(NQ / NWQ), dim3(64 * NWQ), 0, stream,
                           pts, cstart, queries, bbe, out, splits);
    } else {
        hipLaunchKernelGGL(knn_direct_kernel, dim3(NQ / 256), dim3(256), 0, stream,
                           data, queries, out, splits);
    }
    hipLaunchKernelGGL(splits_scan_kernel, dim3(1), dim3(1024), 0, stream, splits);
}